// Round 2
// baseline (936.798 us; speedup 1.0000x reference)
//
#include <hip/hip_runtime.h>

typedef __attribute__((ext_vector_type(4))) float f32x4;
typedef __attribute__((ext_vector_type(8))) short s16x8;

__device__ inline unsigned short f2bf(float x) {
  union { float f; unsigned u; } un; un.f = x;
  unsigned u = un.u;
  u += 0x7FFFu + ((u >> 16) & 1u);
  return (unsigned short)(u >> 16);
}
__device__ inline float bf2f(unsigned short h) {
  union { unsigned u; float f; } un; un.u = ((unsigned)h) << 16; return un.f;
}

__device__ inline f32x4 mfma16(s16x8 a, s16x8 b, f32x4 c) {
  f32x4 d;
  asm("v_mfma_f32_16x16x32_bf16 %0, %1, %2, %3" : "=v"(d) : "v"(a), "v"(b), "v"(c));
  return d;
}

// ---------------------------------------------------------------------------
// GEMM: C[M,N] = act(A[M,K] @ W[K,N] + bias) (+resid). A f32 or bf16, W f32.
// Tiles 128x128xBK32, 256 threads (4 waves), each wave 64x64 (4x4 frags).
// SPLIT: split-bf16 (hi+lo) on both operands -> ~f32 accuracy (3 MFMAs/step).
// ---------------------------------------------------------------------------
template<bool SPLIT, bool A_BF16, bool RELU, bool RESID, bool OUT_BF16>
__global__ __launch_bounds__(256) void gemm_k(
    const void* __restrict__ Ap, const float* __restrict__ W,
    const float* __restrict__ bias, const float* __restrict__ resid,
    void* __restrict__ Cp, int M, int N, int K)
{
  __shared__ __align__(16) unsigned short As[(SPLIT ? 2 : 1) * 128 * 32];
  __shared__ __align__(16) unsigned short Bs[(SPLIT ? 2 : 1) * 128 * 32];
  const int LO = 128 * 32;
  const int tid = threadIdx.x;
  const int lane = tid & 63;
  const int w = tid >> 6;
  const int wm = w >> 1, wn = w & 1;
  const int li = lane & 15, g = lane >> 4;
  const int m0 = blockIdx.y * 128;
  const int n0 = blockIdx.x * 128;

  f32x4 acc[4][4] = {};

  const int ra = tid >> 1;            // A staging: row 0..127
  const int ka = (tid & 1) * 16;      // 16 k-elems per thread
  const int kb = tid >> 3;            // B staging: k-row 0..31
  const int nb = (tid & 7) * 16;      // 16 n-cols per thread

  for (int k0 = 0; k0 < K; k0 += 32) {
    __syncthreads();
    // ---- stage A tile [128][32] bf16 (swizzled 16B slots) ----
    {
      unsigned short th[16], tl[16];
      if (A_BF16) {
        const unsigned short* A = (const unsigned short*)Ap + (size_t)(m0 + ra) * K + k0 + ka;
        *(s16x8*)&th[0] = *(const s16x8*)&A[0];
        *(s16x8*)&th[8] = *(const s16x8*)&A[8];
      } else {
        const float* A = (const float*)Ap + (size_t)(m0 + ra) * K + k0 + ka;
#pragma unroll
        for (int i = 0; i < 4; i++) {
          f32x4 v = *(const f32x4*)&A[4 * i];
#pragma unroll
          for (int j = 0; j < 4; j++) {
            unsigned short h = f2bf(v[j]);
            th[4 * i + j] = h;
            if (SPLIT) tl[4 * i + j] = f2bf(v[j] - bf2f(h));
          }
        }
      }
#pragma unroll
      for (int i = 0; i < 2; i++) {
        int slot = ((ka >> 3) + i) ^ (ra & 3);
        *(s16x8*)&As[ra * 32 + slot * 8] = *(s16x8*)&th[8 * i];
        if (SPLIT) *(s16x8*)&As[LO + ra * 32 + slot * 8] = *(s16x8*)&tl[8 * i];
      }
    }
    // ---- stage B^T tile: Bs[nloc][k], nloc 0..127, k 0..31 ----
    {
      const float* Bg = W + (size_t)(k0 + kb) * N + n0 + nb;
#pragma unroll
      for (int i = 0; i < 4; i++) {
        f32x4 v = *(const f32x4*)&Bg[4 * i];
#pragma unroll
        for (int j = 0; j < 4; j++) {
          int nloc = nb + 4 * i + j;
          int slot = (kb >> 3) ^ (nloc & 3);
          unsigned short h = f2bf(v[j]);
          Bs[nloc * 32 + slot * 8 + (kb & 7)] = h;
          if (SPLIT) Bs[LO + nloc * 32 + slot * 8 + (kb & 7)] = f2bf(v[j] - bf2f(h));
        }
      }
    }
    __syncthreads();
    // ---- compute ----
    s16x8 afr[4], bfr[4], alo[4], blo[4];
#pragma unroll
    for (int mt = 0; mt < 4; mt++) {
      int row = wm * 64 + mt * 16 + li;
      int slot = g ^ (row & 3);
      afr[mt] = *(const s16x8*)&As[row * 32 + slot * 8];
      if (SPLIT) alo[mt] = *(const s16x8*)&As[LO + row * 32 + slot * 8];
    }
#pragma unroll
    for (int nt = 0; nt < 4; nt++) {
      int nrow = wn * 64 + nt * 16 + li;
      int slot = g ^ (nrow & 3);
      bfr[nt] = *(const s16x8*)&Bs[nrow * 32 + slot * 8];
      if (SPLIT) blo[nt] = *(const s16x8*)&Bs[LO + nrow * 32 + slot * 8];
    }
#pragma unroll
    for (int mt = 0; mt < 4; mt++)
#pragma unroll
      for (int nt = 0; nt < 4; nt++) {
        acc[mt][nt] = mfma16(afr[mt], bfr[nt], acc[mt][nt]);
        if (SPLIT) {
          acc[mt][nt] = mfma16(afr[mt], blo[nt], acc[mt][nt]);
          acc[mt][nt] = mfma16(alo[mt], bfr[nt], acc[mt][nt]);
        }
      }
  }
  // ---- epilogue ----
#pragma unroll
  for (int mt = 0; mt < 4; mt++) {
    int mrow = m0 + wm * 64 + mt * 16 + 4 * g;
#pragma unroll
    for (int nt = 0; nt < 4; nt++) {
      int ncol = n0 + wn * 64 + nt * 16 + li;
      float bv = bias ? bias[ncol] : 0.f;
#pragma unroll
      for (int r = 0; r < 4; r++) {
        int mr = mrow + r;
        float v = acc[mt][nt][r] + bv;
        if (RESID) v += resid[(size_t)mr * N + ncol];
        if (RELU) v = fmaxf(v, 0.f);
        if (OUT_BF16) ((unsigned short*)Cp)[(size_t)mr * N + ncol] = f2bf(v);
        else          ((float*)Cp)[(size_t)mr * N + ncol] = v;
      }
    }
  }
}

// ---------------------------------------------------------------------------
// rel coefficients: A[bhq] = sum_d q[d]*(d+1024), S[bhq] = sum_d q[d]
// one wave per (b,h,q) row; lane = d.
// ---------------------------------------------------------------------------
__global__ __launch_bounds__(256) void relcoef_k(const float* __restrict__ Qp,
    float* __restrict__ relA, float* __restrict__ relS)
{
  int wid = blockIdx.x * 4 + (threadIdx.x >> 6);   // 0..65535
  int lane = threadIdx.x & 63;
  int b = wid >> 14;
  int q = wid & 1023;
  int h = (wid >> 10) & 15;
  float v = Qp[(size_t)(b * 1024 + q) * 1024 + h * 64 + lane];
  float a = v * (float)(lane + 1024);
  float s = v;
#pragma unroll
  for (int off = 32; off > 0; off >>= 1) {
    a += __shfl_down(a, off, 64);
    s += __shfl_down(s, off, 64);
  }
  if (lane == 0) { relA[wid] = a; relS[wid] = s; }
}

// ---------------------------------------------------------------------------
// Fused attention with rel-skew + online softmax.
// grid (bh=64, qb=16); 256 thr = 4 waves; wave owns 16 q-rows; KV blk = 64.
// skew[q,k] = A[q]-(k-q+1023)S[q]  (k<=q) ; 0 (k==q+1) ; A[q+1]-(k-q-2)S[q+1]
// ---------------------------------------------------------------------------
template<bool CAUSAL>
__global__ __launch_bounds__(256) void attn_k(
    const float* __restrict__ Qp, const float* __restrict__ KVp,
    const float* __restrict__ relA, const float* __restrict__ relS,
    float* __restrict__ Op)
{
  const int bh = blockIdx.x;
  const int b = bh >> 4, h = bh & 15;
  const int qb = blockIdx.y;
  const int tid = threadIdx.x, lane = tid & 63, w = tid >> 6;
  const int g = lane >> 4, li = lane & 15;

  __shared__ __align__(16) unsigned short Kt[64 * 64];   // [k][d]
  __shared__ __align__(16) unsigned short KT[64 * 64];   // [d][k]
  __shared__ __align__(16) unsigned short Pl[4][16 * 64];

  const int q0 = qb * 64 + w * 16;

  // Q fragments (rows q0+li, d = 8g + 32ks + j)
  s16x8 qf[2];
  {
    const float* qrow = Qp + (size_t)(b * 1024 + q0 + li) * 1024 + h * 64;
#pragma unroll
    for (int ks = 0; ks < 2; ks++) {
      unsigned short t[8];
#pragma unroll
      for (int i = 0; i < 2; i++) {
        f32x4 v = *(const f32x4*)&qrow[8 * g + 32 * ks + 4 * i];
#pragma unroll
        for (int j = 0; j < 4; j++) t[4 * i + j] = f2bf(v[j]);
      }
      qf[ks] = *(s16x8*)t;
    }
  }
  // rel coefs for this lane's 4 D-rows (and +1 rows for the k>q+1 branch)
  float rA[4], rS[4], rA1[4], rS1[4];
#pragma unroll
  for (int r = 0; r < 4; r++) {
    int q = q0 + 4 * g + r;
    rA[r] = relA[bh * 1024 + q];  rS[r] = relS[bh * 1024 + q];
    int q1 = (q + 1 < 1024) ? q + 1 : 1023;
    rA1[r] = relA[bh * 1024 + q1]; rS1[r] = relS[bh * 1024 + q1];
  }

  float mrow[4], lrow[4];
#pragma unroll
  for (int r = 0; r < 4; r++) { mrow[r] = -3.0e38f; lrow[r] = 0.f; }
  f32x4 accO[4] = {};

  const int nkb = CAUSAL ? (qb + 1) : 16;
  for (int kbk = 0; kbk < nkb; kbk++) {
    __syncthreads();
    // ---- stage K[k][d] and KT[d][k] (bf16, swizzled 16B slots) ----
    {
      int krow = tid >> 2;
      int cb = (tid & 3) * 16;
      const float* src = KVp + (size_t)(b * 1024 + kbk * 64 + krow) * 1024 + h * 64 + cb;
      unsigned short tmp[16];
#pragma unroll
      for (int i = 0; i < 4; i++) {
        f32x4 v = *(const f32x4*)&src[4 * i];
#pragma unroll
        for (int j = 0; j < 4; j++) tmp[4 * i + j] = f2bf(v[j]);
      }
#pragma unroll
      for (int i = 0; i < 2; i++) {
        int slot = ((cb >> 3) + i) ^ (krow & 7);
        *(s16x8*)&Kt[krow * 64 + slot * 8] = *(s16x8*)&tmp[8 * i];
      }
#pragma unroll
      for (int j = 0; j < 16; j++) {
        int d = cb + j;
        int slot = (krow >> 3) ^ (d & 7);
        KT[d * 64 + slot * 8 + (krow & 7)] = tmp[j];
      }
    }
    __syncthreads();
    // ---- S = Q K^T ----
    f32x4 accS[4];
#pragma unroll
    for (int nt = 0; nt < 4; nt++) {
      int krow = li + 16 * nt;
      f32x4 c = {};
#pragma unroll
      for (int ks = 0; ks < 2; ks++) {
        int slot = (g + 4 * ks) ^ (krow & 7);
        s16x8 kf = *(const s16x8*)&Kt[krow * 64 + slot * 8];
        c = mfma16(qf[ks], kf, c);
      }
      accS[nt] = c;
    }
    // ---- skew + mask + online softmax ----
    float pv[4][4];
    float bm[4];
#pragma unroll
    for (int r = 0; r < 4; r++) bm[r] = -3.0e38f;
#pragma unroll
    for (int nt = 0; nt < 4; nt++) {
      int kk = kbk * 64 + 16 * nt + li;
#pragma unroll
      for (int r = 0; r < 4; r++) {
        int q = q0 + 4 * g + r;
        float sk;
        if (kk <= q)           sk = rA[r] - (float)(kk - q + 1023) * rS[r];
        else if (kk == q + 1)  sk = 0.f;
        else                   sk = rA1[r] - (float)(kk - q - 2) * rS1[r];
        float lg = (accS[nt][r] + sk) * 0.125f;
        if (CAUSAL && kk > q) lg = -1.0e9f;
        pv[nt][r] = lg;
        bm[r] = fmaxf(bm[r], lg);
      }
    }
#pragma unroll
    for (int off = 1; off < 16; off <<= 1)
#pragma unroll
      for (int r = 0; r < 4; r++)
        bm[r] = fmaxf(bm[r], __shfl_xor(bm[r], off, 64));
    float scl[4], rsum[4];
#pragma unroll
    for (int r = 0; r < 4; r++) {
      float mnew = fmaxf(mrow[r], bm[r]);
      scl[r] = __expf(mrow[r] - mnew);
      mrow[r] = mnew;
      rsum[r] = 0.f;
    }
#pragma unroll
    for (int nt = 0; nt < 4; nt++)
#pragma unroll
      for (int r = 0; r < 4; r++) {
        float p = __expf(pv[nt][r] - mrow[r]);
        pv[nt][r] = p;
        rsum[r] += p;
      }
#pragma unroll
    for (int off = 1; off < 16; off <<= 1)
#pragma unroll
      for (int r = 0; r < 4; r++)
        rsum[r] += __shfl_xor(rsum[r], off, 64);
#pragma unroll
    for (int r = 0; r < 4; r++) lrow[r] = lrow[r] * scl[r] + rsum[r];
    // ---- write P (bf16) to per-wave LDS ----
#pragma unroll
    for (int nt = 0; nt < 4; nt++)
#pragma unroll
      for (int r = 0; r < 4; r++) {
        int qq = 4 * g + r;
        int kkk = 16 * nt + li;
        int slot = (kkk >> 3) ^ (qq & 7);
        Pl[w][qq * 64 + slot * 8 + (kkk & 7)] = f2bf(pv[nt][r]);
      }
    // rescale O
#pragma unroll
    for (int dt = 0; dt < 4; dt++)
#pragma unroll
      for (int r = 0; r < 4; r++) accO[dt][r] *= scl[r];
    __syncthreads();
    // ---- O += P @ V  (V == K; B-frag from KT[d][k]) ----
#pragma unroll
    for (int dt = 0; dt < 4; dt++) {
#pragma unroll
      for (int ks = 0; ks < 2; ks++) {
        int slotA = (g + 4 * ks) ^ (li & 7);
        s16x8 pf = *(const s16x8*)&Pl[w][li * 64 + slotA * 8];
        int drow = li + 16 * dt;
        int slotB = (g + 4 * ks) ^ (drow & 7);
        s16x8 vf = *(const s16x8*)&KT[drow * 64 + slotB * 8];
        accO[dt] = mfma16(pf, vf, accO[dt]);
      }
    }
  }
  // ---- epilogue: O / l ----
#pragma unroll
  for (int dt = 0; dt < 4; dt++) {
    int dcol = h * 64 + li + 16 * dt;
#pragma unroll
    for (int r = 0; r < 4; r++) {
      int q = q0 + 4 * g + r;
      Op[(size_t)(b * 1024 + q) * 1024 + dcol] = accO[dt][r] / lrow[r];
    }
  }
}

// ---------------------------------------------------------------------------
// LayerNorm over rows of 1024 (in-place safe: row held in regs).
// ---------------------------------------------------------------------------
__global__ __launch_bounds__(256) void ln_k(const float* __restrict__ X,
    const float* __restrict__ gw, const float* __restrict__ bw,
    float* __restrict__ O)
{
  int row = blockIdx.x;
  const float* x = X + (size_t)row * 1024;
  int tid = threadIdx.x;
  f32x4 v = *(const f32x4*)&x[tid * 4];
  float s = v[0] + v[1] + v[2] + v[3];
  float s2 = v[0]*v[0] + v[1]*v[1] + v[2]*v[2] + v[3]*v[3];
#pragma unroll
  for (int off = 32; off > 0; off >>= 1) {
    s += __shfl_down(s, off, 64);
    s2 += __shfl_down(s2, off, 64);
  }
  __shared__ float rb[8];
  if ((tid & 63) == 0) { rb[tid >> 6] = s; rb[4 + (tid >> 6)] = s2; }
  __syncthreads();
  float S = rb[0] + rb[1] + rb[2] + rb[3];
  float S2 = rb[4] + rb[5] + rb[6] + rb[7];
  float mu = S * (1.f / 1024.f);
  float var = S2 * (1.f / 1024.f) - mu * mu;
  float rstd = rsqrtf(var + 1e-5f);
  f32x4 go = *(const f32x4*)&gw[tid * 4];
  f32x4 bo = *(const f32x4*)&bw[tid * 4];
  f32x4 r;
#pragma unroll
  for (int j = 0; j < 4; j++) r[j] = (v[j] - mu) * rstd * go[j] + bo[j];
  *(f32x4*)&(O + (size_t)row * 1024)[tid * 4] = r;
}

// ---------------------------------------------------------------------------
extern "C" void kernel_launch(void* const* d_in, const int* in_sizes, int n_in,
                              void* d_out, int out_size, void* d_ws, size_t ws_size,
                              hipStream_t stream)
{
  const float* tgt  = (const float*)d_in[0];
  const float* mem  = (const float*)d_in[1];
  const float* saWq = (const float*)d_in[3];
  const float* sabq = (const float*)d_in[4];
  const float* saWo = (const float*)d_in[5];
  const float* sabo = (const float*)d_in[6];
  const float* caWq = (const float*)d_in[7];
  const float* cabq = (const float*)d_in[8];
  const float* caWo = (const float*)d_in[9];
  const float* cabo = (const float*)d_in[10];
  const float* W1   = (const float*)d_in[11];
  const float* b1   = (const float*)d_in[12];
  const float* W2   = (const float*)d_in[13];
  const float* b2   = (const float*)d_in[14];
  const float* g1   = (const float*)d_in[15];
  const float* be1  = (const float*)d_in[16];
  const float* g2   = (const float*)d_in[17];
  const float* be2  = (const float*)d_in[18];
  const float* g3   = (const float*)d_in[19];
  const float* be3  = (const float*)d_in[20];
  float* out = (float*)d_out;

  char* ws = (char*)d_ws;
  const size_t SZ = (size_t)4096 * 1024;
  float* qkv  = (float*)ws; ws += SZ * 4;
  float* attn = (float*)ws; ws += SZ * 4;
  float* x1   = (float*)ws; ws += SZ * 4;
  float* qca  = (float*)ws; ws += SZ * 4;
  float* kvca = (float*)ws; ws += SZ * 4;
  float* x2   = (float*)ws; ws += SZ * 4;
  unsigned short* hbuf = (unsigned short*)ws; ws += (size_t)4096 * 4096 * 2;
  float* rA = (float*)ws; ws += 65536 * 4;
  float* rS = (float*)ws; ws += 65536 * 4;

  dim3 blk(256);
  dim3 gNarrow(8, 32);    // N=1024, M=4096
  dim3 gWide(32, 32);     // N=4096, M=4096

  // 1. SA qkv = tgt @ saWq + sabq   (q == k == v) -- SPLIT (feeds rel coefs)
  gemm_k<true, false, false, false, false><<<gNarrow, blk, 0, stream>>>(tgt, saWq, sabq, nullptr, qkv, 4096, 1024, 1024);
  // 2. rel coefficients from SA q
  relcoef_k<<<dim3(16384), blk, 0, stream>>>(qkv, rA, rS);
  // 3. causal attention
  attn_k<true><<<dim3(64, 16), blk, 0, stream>>>(qkv, qkv, rA, rS, attn);
  // 4. x1 = attn @ saWo + sabo + tgt ; 5. LN1 in place
  gemm_k<false, false, false, true, false><<<gNarrow, blk, 0, stream>>>(attn, saWo, sabo, tgt, x1, 4096, 1024, 1024);
  ln_k<<<dim3(4096), blk, 0, stream>>>(x1, g1, be1, x1);
  // 6/7. CA projections -- SPLIT (q feeds rel coefs; kv same weights)
  gemm_k<true, false, false, false, false><<<gNarrow, blk, 0, stream>>>(x1, caWq, cabq, nullptr, qca, 4096, 1024, 1024);
  gemm_k<true, false, false, false, false><<<gNarrow, blk, 0, stream>>>(mem, caWq, cabq, nullptr, kvca, 4096, 1024, 1024);
  // 8. rel coefficients from CA q
  relcoef_k<<<dim3(16384), blk, 0, stream>>>(qca, rA, rS);
  // 9. cross attention (no mask -> skew wrap entries live)
  attn_k<false><<<dim3(64, 16), blk, 0, stream>>>(qca, kvca, rA, rS, attn);
  // 10. x2 = attn @ caWo + cabo + x1 ; 11. LN2 in place
  gemm_k<false, false, false, true, false><<<gNarrow, blk, 0, stream>>>(attn, caWo, cabo, x1, x2, 4096, 1024, 1024);
  ln_k<<<dim3(4096), blk, 0, stream>>>(x2, g2, be2, x2);
  // 12. h = relu(x2 @ W1 + b1) -> bf16
  gemm_k<false, false, true, false, true><<<gWide, blk, 0, stream>>>(x2, W1, b1, nullptr, hbuf, 4096, 4096, 1024);
  // 13. out = h @ W2 + b2 + x2 ; 14. LN3 in place on d_out
  gemm_k<false, true, false, true, false><<<gNarrow, blk, 0, stream>>>(hbuf, W2, b2, x2, out, 4096, 1024, 4096);
  ln_k<<<dim3(4096), blk, 0, stream>>>(out, g3, be3, out);

  (void)in_sizes; (void)n_in; (void)out_size; (void)ws_size;
}

// Round 5
// 533.037 us; speedup vs baseline: 1.7575x; 1.7575x over previous
//
#include <hip/hip_runtime.h>

typedef __attribute__((ext_vector_type(4))) float f32x4;
typedef __attribute__((ext_vector_type(8))) short s16x8;
typedef __attribute__((ext_vector_type(4))) unsigned short u16x4;

__device__ __forceinline__ unsigned short f2bf(float x) {
  union { float f; unsigned u; } un; un.f = x;
  unsigned u = un.u;
  u += 0x7FFFu + ((u >> 16) & 1u);
  return (unsigned short)(u >> 16);
}
__device__ __forceinline__ float bf2f(unsigned short h) {
  union { unsigned u; float f; } un; un.u = ((unsigned)h) << 16; return un.f;
}

__device__ __forceinline__ f32x4 mfma16(s16x8 a, s16x8 b, f32x4 c) {
  f32x4 d;
  asm("v_mfma_f32_16x16x32_bf16 %0, %1, %2, %3" : "=v"(d) : "v"(a), "v"(b), "v"(c));
  return d;
}

__device__ __forceinline__ void gld16(const void* g, void* l) {
  __builtin_amdgcn_global_load_lds(
      (const __attribute__((address_space(1))) void*)g,
      (__attribute__((address_space(3))) void*)l, 16, 0, 0);
}

// ---------------------------------------------------------------------------
// bf16 GEMM, m97-style: A[M][K] bf16, B[N][K] bf16 (pre-transposed weight).
// 128x128 tile, BK=64, 256 thr (4 waves, 2x2), global_load_lds staging with
// pre-swizzled source, double-buffered LDS, counted vmcnt(8) prefetch.
// RACE FIX (R4->R5): raw s_barrier is NOT a compiler fence; sched_barrier(0)
// on both sides of each barrier pins ds_read/gld16 to the correct side.
// ---------------------------------------------------------------------------
template<bool RELU, bool RESID, bool OUT_BF16>
__global__ __launch_bounds__(256, 2) void bgemm_k(
    const unsigned short* __restrict__ Ab, const unsigned short* __restrict__ Bb,
    const float* __restrict__ bias, const float* __restrict__ resid,
    void* __restrict__ Cp, int M, int N, int K, int lbx)
{
  __shared__ __align__(16) unsigned short As[2][128 * 64];
  __shared__ __align__(16) unsigned short Bs[2][128 * 64];

  const int nwg = gridDim.x;
  const int bid = blockIdx.x;
  const int swz = (bid & 7) * (nwg >> 3) + (bid >> 3);
  const int nbx_m1 = (1 << lbx) - 1;
  const int n0 = (swz & nbx_m1) * 128;
  const int m0 = (swz >> lbx) * 128;

  const int tid = threadIdx.x;
  const int lane = tid & 63;
  const int w = tid >> 6;
  const int wm = w >> 1, wn = w & 1;
  const int li = lane & 15, g = lane >> 4;

  f32x4 acc[4][4] = {};

#define STAGE(buf, kt) do { \
    const int k0_ = (kt) * 64; \
    _Pragma("unroll") \
    for (int i_ = 0; i_ < 4; i_++) { \
      int lin = i_ * 256 + tid; int row = lin >> 3; \
      int cg = (lin & 7) ^ (row & 7); \
      gld16(Ab + (size_t)(m0 + row) * K + k0_ + cg * 8, &As[buf][lin * 8]); \
    } \
    _Pragma("unroll") \
    for (int i_ = 0; i_ < 4; i_++) { \
      int lin = i_ * 256 + tid; int row = lin >> 3; \
      int cg = (lin & 7) ^ (row & 7); \
      gld16(Bb + (size_t)(n0 + row) * K + k0_ + cg * 8, &Bs[buf][lin * 8]); \
    } \
  } while (0)

  const int NT = K >> 6;
  STAGE(0, 0);
  for (int t = 0; t < NT; ++t) {
    const int cur = t & 1;
    if (t + 1 < NT) {
      STAGE(cur ^ 1, t + 1);
      asm volatile("s_waitcnt vmcnt(8)" ::: "memory");
    } else {
      asm volatile("s_waitcnt vmcnt(0)" ::: "memory");
    }
    __builtin_amdgcn_sched_barrier(0);
    __builtin_amdgcn_s_barrier();
    __builtin_amdgcn_sched_barrier(0);
#pragma unroll
    for (int ks = 0; ks < 2; ++ks) {
      s16x8 af[4], bf[4];
#pragma unroll
      for (int mt = 0; mt < 4; mt++) {
        int row = wm * 64 + mt * 16 + li;
        int slot = (4 * ks + g) ^ (row & 7);
        af[mt] = *(const s16x8*)&As[cur][row * 64 + slot * 8];
      }
#pragma unroll
      for (int nt = 0; nt < 4; nt++) {
        int row = wn * 64 + nt * 16 + li;
        int slot = (4 * ks + g) ^ (row & 7);
        bf[nt] = *(const s16x8*)&Bs[cur][row * 64 + slot * 8];
      }
#pragma unroll
      for (int mt = 0; mt < 4; mt++)
#pragma unroll
        for (int nt = 0; nt < 4; nt++)
          acc[mt][nt] = mfma16(af[mt], bf[nt], acc[mt][nt]);
    }
    __builtin_amdgcn_sched_barrier(0);
    __builtin_amdgcn_s_barrier();
    __builtin_amdgcn_sched_barrier(0);
  }
#undef STAGE

#pragma unroll
  for (int mt = 0; mt < 4; mt++) {
    int mrow = m0 + wm * 64 + mt * 16 + 4 * g;
#pragma unroll
    for (int nt = 0; nt < 4; nt++) {
      int ncol = n0 + wn * 64 + nt * 16 + li;
      float bv = bias ? bias[ncol] : 0.f;
#pragma unroll
      for (int r = 0; r < 4; r++) {
        int mr = mrow + r;
        float v = acc[mt][nt][r] + bv;
        if (RESID) v += resid[(size_t)mr * N + ncol];
        if (RELU) v = fmaxf(v, 0.f);
        if (OUT_BF16) ((unsigned short*)Cp)[(size_t)mr * N + ncol] = f2bf(v);
        else          ((float*)Cp)[(size_t)mr * N + ncol] = v;
      }
    }
  }
}

// ---------------------------------------------------------------------------
// Split-bf16 projection GEMM (~f32 accurate): A f32 [M][K]; B hi/lo bf16
// [N][K] pre-transposed. acc = ah*bh + ah*bl + al*bh. Single-buffered 64KB
// LDS, 2 blocks/CU, __syncthreads (full fence) structure — race-safe.
// ---------------------------------------------------------------------------
__global__ __launch_bounds__(256, 2) void sgemm_k(
    const float* __restrict__ Af, const unsigned short* __restrict__ Bh,
    const unsigned short* __restrict__ Bl, const float* __restrict__ bias,
    unsigned short* __restrict__ Cb, int M, int N, int K, int lbx)
{
  __shared__ __align__(16) unsigned short AsH[128 * 64];
  __shared__ __align__(16) unsigned short AsL[128 * 64];
  __shared__ __align__(16) unsigned short BsH[128 * 64];
  __shared__ __align__(16) unsigned short BsL[128 * 64];

  const int nwg = gridDim.x;
  const int bid = blockIdx.x;
  const int swz = (bid & 7) * (nwg >> 3) + (bid >> 3);
  const int nbx_m1 = (1 << lbx) - 1;
  const int n0 = (swz & nbx_m1) * 128;
  const int m0 = (swz >> lbx) * 128;

  const int tid = threadIdx.x;
  const int lane = tid & 63;
  const int w = tid >> 6;
  const int wm = w >> 1, wn = w & 1;
  const int li = lane & 15, g = lane >> 4;

  f32x4 acc[4][4] = {};

  const int NT = K >> 6;
  for (int t = 0; t < NT; ++t) {
    __syncthreads();
#pragma unroll
    for (int i = 0; i < 4; i++) {
      int lin = i * 256 + tid; int row = lin >> 3;
      int cg = (lin & 7) ^ (row & 7);
      gld16(Bh + (size_t)(n0 + row) * K + t * 64 + cg * 8, &BsH[lin * 8]);
      gld16(Bl + (size_t)(n0 + row) * K + t * 64 + cg * 8, &BsL[lin * 8]);
    }
#pragma unroll
    for (int p = 0; p < 4; p++) {
      int arow = p * 32 + (tid >> 3);
      int colb = (tid & 7) * 8;
      const float* src = Af + (size_t)(m0 + arow) * K + t * 64 + colb;
      f32x4 v0 = *(const f32x4*)&src[0];
      f32x4 v1 = *(const f32x4*)&src[4];
      unsigned short th[8], tl[8];
#pragma unroll
      for (int j = 0; j < 4; j++) {
        unsigned short h0 = f2bf(v0[j]); th[j] = h0;     tl[j] = f2bf(v0[j] - bf2f(h0));
        unsigned short h1 = f2bf(v1[j]); th[4 + j] = h1; tl[4 + j] = f2bf(v1[j] - bf2f(h1));
      }
      int slot = (tid & 7) ^ (arow & 7);
      *(s16x8*)&AsH[arow * 64 + slot * 8] = *(s16x8*)th;
      *(s16x8*)&AsL[arow * 64 + slot * 8] = *(s16x8*)tl;
    }
    asm volatile("s_waitcnt vmcnt(0)" ::: "memory");
    __syncthreads();
#pragma unroll
    for (int ks = 0; ks < 2; ++ks) {
      s16x8 ah[4], al[4], bh[4], bl[4];
#pragma unroll
      for (int mt = 0; mt < 4; mt++) {
        int row = wm * 64 + mt * 16 + li;
        int slot = (4 * ks + g) ^ (row & 7);
        ah[mt] = *(const s16x8*)&AsH[row * 64 + slot * 8];
        al[mt] = *(const s16x8*)&AsL[row * 64 + slot * 8];
      }
#pragma unroll
      for (int nt = 0; nt < 4; nt++) {
        int row = wn * 64 + nt * 16 + li;
        int slot = (4 * ks + g) ^ (row & 7);
        bh[nt] = *(const s16x8*)&BsH[row * 64 + slot * 8];
        bl[nt] = *(const s16x8*)&BsL[row * 64 + slot * 8];
      }
#pragma unroll
      for (int mt = 0; mt < 4; mt++)
#pragma unroll
        for (int nt = 0; nt < 4; nt++) {
          acc[mt][nt] = mfma16(ah[mt], bh[nt], acc[mt][nt]);
          acc[mt][nt] = mfma16(ah[mt], bl[nt], acc[mt][nt]);
          acc[mt][nt] = mfma16(al[mt], bh[nt], acc[mt][nt]);
        }
    }
  }

#pragma unroll
  for (int mt = 0; mt < 4; mt++) {
    int mrow = m0 + wm * 64 + mt * 16 + 4 * g;
#pragma unroll
    for (int nt = 0; nt < 4; nt++) {
      int ncol = n0 + wn * 64 + nt * 16 + li;
      float bv = bias[ncol];
#pragma unroll
      for (int r = 0; r < 4; r++) {
        int mr = mrow + r;
        Cb[(size_t)mr * N + ncol] = f2bf(acc[mt][nt][r] + bv);
      }
    }
  }
}

// ---------------------------------------------------------------------------
// W[K][N] f32 -> WT[N][K] bf16 (64x64 LDS tiles)
// ---------------------------------------------------------------------------
__global__ __launch_bounds__(256) void transpose_cvt_k(const float* __restrict__ W,
    unsigned short* __restrict__ WT, int K, int N)
{
  __shared__ unsigned short Ls[64][65];
  int ntx = N >> 6;
  int ty = blockIdx.x / ntx, tx = blockIdx.x - ty * ntx;
  int r0 = ty << 6, c0 = tx << 6;
  int tid = threadIdx.x;
  int rl = tid >> 4, cl = (tid & 15) << 2;
#pragma unroll
  for (int rr = 0; rr < 4; rr++) {
    f32x4 v = *(const f32x4*)&W[(size_t)(r0 + rl + rr * 16) * N + c0 + cl];
#pragma unroll
    for (int j = 0; j < 4; j++) Ls[rl + rr * 16][cl + j] = f2bf(v[j]);
  }
  __syncthreads();
#pragma unroll
  for (int rr = 0; rr < 4; rr++) {
    int nl = rl + rr * 16;
    u16x4 o;
#pragma unroll
    for (int j = 0; j < 4; j++) o[j] = Ls[cl + j][nl];
    *(u16x4*)&WT[(size_t)(c0 + nl) * K + r0 + cl] = o;
  }
}

// ---------------------------------------------------------------------------
// W[K][N] f32 -> hi/lo bf16 [N][K] transposed pair
// ---------------------------------------------------------------------------
__global__ __launch_bounds__(256) void transpose_cvt2_k(const float* __restrict__ W,
    unsigned short* __restrict__ WTh, unsigned short* __restrict__ WTl, int K, int N)
{
  __shared__ float Ls[64][65];
  int ntx = N >> 6;
  int ty = blockIdx.x / ntx, tx = blockIdx.x - ty * ntx;
  int r0 = ty << 6, c0 = tx << 6;
  int tid = threadIdx.x;
  int rl = tid >> 4, cl = (tid & 15) << 2;
#pragma unroll
  for (int rr = 0; rr < 4; rr++) {
    f32x4 v = *(const f32x4*)&W[(size_t)(r0 + rl + rr * 16) * N + c0 + cl];
#pragma unroll
    for (int j = 0; j < 4; j++) Ls[rl + rr * 16][cl + j] = v[j];
  }
  __syncthreads();
#pragma unroll
  for (int rr = 0; rr < 4; rr++) {
    int nl = rl + rr * 16;
    u16x4 oh, ol;
#pragma unroll
    for (int j = 0; j < 4; j++) {
      float v = Ls[cl + j][nl];
      unsigned short h = f2bf(v);
      oh[j] = h; ol[j] = f2bf(v - bf2f(h));
    }
    *(u16x4*)&WTh[(size_t)(c0 + nl) * K + r0 + cl] = oh;
    *(u16x4*)&WTl[(size_t)(c0 + nl) * K + r0 + cl] = ol;
  }
}

// ---------------------------------------------------------------------------
// wrel[k][0..15]=sum_d Wq[k][64h+d]*(d+1024); wrel[k][16..31]=sum_d Wq[k][64h+d]
// ---------------------------------------------------------------------------
__global__ __launch_bounds__(256) void wrelbuild_k(const float* __restrict__ Wq,
    float* __restrict__ Wr)
{
  int idx = blockIdx.x * 256 + threadIdx.x;
  int k = idx >> 4, h = idx & 15;
  const float* src = Wq + (size_t)k * 1024 + h * 64;
  float a = 0.f, s = 0.f;
#pragma unroll
  for (int d = 0; d < 64; d += 4) {
    f32x4 v = *(const f32x4*)&src[d];
#pragma unroll
    for (int j = 0; j < 4; j++) { a += v[j] * (float)(d + j + 1024); s += v[j]; }
  }
  Wr[k * 32 + h] = a;
  Wr[k * 32 + 16 + h] = s;
}

__global__ __launch_bounds__(64) void crel_k(const float* __restrict__ bq,
    float* __restrict__ cr)
{
  int h = threadIdx.x;
  if (h < 16) {
    float a = 0.f, s = 0.f;
    for (int d = 0; d < 64; d++) { float v = bq[h * 64 + d]; a += v * (float)(d + 1024); s += v; }
    cr[h] = a; cr[16 + h] = s;
  }
}

// ---------------------------------------------------------------------------
// rel coefficients mini-GEMM (f32-exact): Out[4096][32] = X[4096][1024]@Wr + cr
// ---------------------------------------------------------------------------
__global__ __launch_bounds__(256) void relgemm_k(const float* __restrict__ X,
    const float* __restrict__ Wr, const float* __restrict__ cr,
    float* __restrict__ Out)
{
  __shared__ float Xs[8][256];
  __shared__ float Ws[256][32];
  int r0 = blockIdx.x * 8;
  int tid = threadIdx.x;
  int rl = tid >> 5, col = tid & 31;
  float acc = 0.f;
  for (int kc = 0; kc < 1024; kc += 256) {
    __syncthreads();
    {
      const float* xs = X + (size_t)(r0 + rl) * 1024 + kc + col * 8;
      *(f32x4*)&Xs[rl][col * 8] = *(const f32x4*)xs;
      *(f32x4*)&Xs[rl][col * 8 + 4] = *(const f32x4*)(xs + 4);
    }
    {
      const float* wsrc = Wr + (size_t)(kc + tid) * 32;
#pragma unroll
      for (int i = 0; i < 8; i++) *(f32x4*)&Ws[tid][i * 4] = *(const f32x4*)&wsrc[i * 4];
    }
    __syncthreads();
#pragma unroll 8
    for (int kk = 0; kk < 256; ++kk) acc += Xs[rl][kk] * Ws[kk][col];
  }
  Out[(size_t)(r0 + rl) * 32 + col] = acc + cr[col];
}

// ---------------------------------------------------------------------------
// Fused attention (bf16 in/out) with rel-skew + online softmax.
// ---------------------------------------------------------------------------
template<bool CAUSAL>
__global__ __launch_bounds__(256, 2) void attn_k(
    const unsigned short* __restrict__ Qb, const unsigned short* __restrict__ KVb,
    const float* __restrict__ rAS, unsigned short* __restrict__ Ob)
{
  const int bh = blockIdx.x;
  const int b = bh >> 4, h = bh & 15;
  const int qb = blockIdx.y;
  const int tid = threadIdx.x, lane = tid & 63, w = tid >> 6;
  const int g = lane >> 4, li = lane & 15;

  __shared__ __align__(16) unsigned short Kt[64 * 64];
  __shared__ __align__(16) unsigned short KT[64 * 64];
  __shared__ __align__(16) unsigned short Pl[4][16 * 64];

  const int q0 = qb * 64 + w * 16;

  s16x8 qf[2];
  {
    const unsigned short* qrow = Qb + (size_t)(b * 1024 + q0 + li) * 1024 + h * 64;
    qf[0] = *(const s16x8*)&qrow[8 * g];
    qf[1] = *(const s16x8*)&qrow[8 * g + 32];
  }
  float rA[4], rS[4], rA1[4], rS1[4];
#pragma unroll
  for (int r = 0; r < 4; r++) {
    int q = q0 + 4 * g + r;
    rA[r] = rAS[(size_t)(b * 1024 + q) * 32 + h];
    rS[r] = rAS[(size_t)(b * 1024 + q) * 32 + 16 + h];
    int q1 = (q + 1 < 1024) ? q + 1 : 1023;
    rA1[r] = rAS[(size_t)(b * 1024 + q1) * 32 + h];
    rS1[r] = rAS[(size_t)(b * 1024 + q1) * 32 + 16 + h];
  }

  float mrow[4], lrow[4];
#pragma unroll
  for (int r = 0; r < 4; r++) { mrow[r] = -3.0e38f; lrow[r] = 0.f; }
  f32x4 accO[4] = {};

  const int nkb = CAUSAL ? (qb + 1) : 16;
  for (int kbk = 0; kbk < nkb; kbk++) {
    __syncthreads();
    {
      int krow = tid >> 2;
      int seg = tid & 3;
      const unsigned short* src = KVb + (size_t)(b * 1024 + kbk * 64 + krow) * 1024 + h * 64 + seg * 16;
      s16x8 v0 = *(const s16x8*)&src[0];
      s16x8 v1 = *(const s16x8*)&src[8];
      {
        int slot0 = (seg * 2) ^ (krow & 7);
        int slot1 = (seg * 2 + 1) ^ (krow & 7);
        *(s16x8*)&Kt[krow * 64 + slot0 * 8] = v0;
        *(s16x8*)&Kt[krow * 64 + slot1 * 8] = v1;
      }
#pragma unroll
      for (int j = 0; j < 8; j++) {
        int d0 = seg * 16 + j;
        int d1 = seg * 16 + 8 + j;
        KT[d0 * 64 + (((krow >> 3) ^ (d0 & 7)) * 8) + (krow & 7)] = (unsigned short)v0[j];
        KT[d1 * 64 + (((krow >> 3) ^ (d1 & 7)) * 8) + (krow & 7)] = (unsigned short)v1[j];
      }
    }
    __syncthreads();
    f32x4 accS[4];
#pragma unroll
    for (int nt = 0; nt < 4; nt++) {
      int krow = li + 16 * nt;
      f32x4 c = {};
#pragma unroll
      for (int ks = 0; ks < 2; ks++) {
        int slot = (g + 4 * ks) ^ (krow & 7);
        s16x8 kf = *(const s16x8*)&Kt[krow * 64 + slot * 8];
        c = mfma16(qf[ks], kf, c);
      }
      accS[nt] = c;
    }
    float pv[4][4];
    float bm[4];
#pragma unroll
    for (int r = 0; r < 4; r++) bm[r] = -3.0e38f;
#pragma unroll
    for (int nt = 0; nt < 4; nt++) {
      int kk = kbk * 64 + 16 * nt + li;
#pragma unroll
      for (int r = 0; r < 4; r++) {
        int q = q0 + 4 * g + r;
        float sk;
        if (kk <= q)           sk = rA[r] - (float)(kk - q + 1023) * rS[r];
        else if (kk == q + 1)  sk = 0.f;
        else                   sk = rA1[r] - (float)(kk - q - 2) * rS1[r];
        float lg = (accS[nt][r] + sk) * 0.125f;
        if (CAUSAL && kk > q) lg = -1.0e9f;
        pv[nt][r] = lg;
        bm[r] = fmaxf(bm[r], lg);
      }
    }
#pragma unroll
    for (int off = 1; off < 16; off <<= 1)
#pragma unroll
      for (int r = 0; r < 4; r++)
        bm[r] = fmaxf(bm[r], __shfl_xor(bm[r], off, 64));
    float scl[4], rsum[4];
#pragma unroll
    for (int r = 0; r < 4; r++) {
      float mnew = fmaxf(mrow[r], bm[r]);
      scl[r] = __expf(mrow[r] - mnew);
      mrow[r] = mnew;
      rsum[r] = 0.f;
    }
#pragma unroll
    for (int nt = 0; nt < 4; nt++)
#pragma unroll
      for (int r = 0; r < 4; r++) {
        float p = __expf(pv[nt][r] - mrow[r]);
        pv[nt][r] = p;
        rsum[r] += p;
      }
#pragma unroll
    for (int off = 1; off < 16; off <<= 1)
#pragma unroll
      for (int r = 0; r < 4; r++)
        rsum[r] += __shfl_xor(rsum[r], off, 64);
#pragma unroll
    for (int r = 0; r < 4; r++) lrow[r] = lrow[r] * scl[r] + rsum[r];
#pragma unroll
    for (int nt = 0; nt < 4; nt++)
#pragma unroll
      for (int r = 0; r < 4; r++) {
        int qq = 4 * g + r;
        int kkk = 16 * nt + li;
        int slot = (kkk >> 3) ^ (qq & 7);
        Pl[w][qq * 64 + slot * 8 + (kkk & 7)] = f2bf(pv[nt][r]);
      }
#pragma unroll
    for (int dt = 0; dt < 4; dt++)
#pragma unroll
      for (int r = 0; r < 4; r++) accO[dt][r] *= scl[r];
    __syncthreads();
#pragma unroll
    for (int dt = 0; dt < 4; dt++) {
#pragma unroll
      for (int ks = 0; ks < 2; ks++) {
        int slotA = (g + 4 * ks) ^ (li & 7);
        s16x8 pf = *(const s16x8*)&Pl[w][li * 64 + slotA * 8];
        int drow = li + 16 * dt;
        int slotB = (g + 4 * ks) ^ (drow & 7);
        s16x8 vf = *(const s16x8*)&KT[drow * 64 + slotB * 8];
        accO[dt] = mfma16(pf, vf, accO[dt]);
      }
    }
  }
#pragma unroll
  for (int dt = 0; dt < 4; dt++) {
    int dcol = h * 64 + li + 16 * dt;
#pragma unroll
    for (int r = 0; r < 4; r++) {
      int q = q0 + 4 * g + r;
      Ob[(size_t)(b * 1024 + q) * 1024 + dcol] = f2bf(accO[dt][r] / lrow[r]);
    }
  }
}

// ---------------------------------------------------------------------------
// LayerNorm rows of 1024; writes f32 and optional bf16 copy.
// ---------------------------------------------------------------------------
__global__ __launch_bounds__(256) void ln_k(const float* __restrict__ X,
    const float* __restrict__ gw, const float* __restrict__ bw,
    float* __restrict__ O, unsigned short* __restrict__ Ob)
{
  int row = blockIdx.x;
  const float* x = X + (size_t)row * 1024;
  int tid = threadIdx.x;
  f32x4 v = *(const f32x4*)&x[tid * 4];
  float s = v[0] + v[1] + v[2] + v[3];
  float s2 = v[0]*v[0] + v[1]*v[1] + v[2]*v[2] + v[3]*v[3];
#pragma unroll
  for (int off = 32; off > 0; off >>= 1) {
    s += __shfl_down(s, off, 64);
    s2 += __shfl_down(s2, off, 64);
  }
  __shared__ float rb[8];
  if ((tid & 63) == 0) { rb[tid >> 6] = s; rb[4 + (tid >> 6)] = s2; }
  __syncthreads();
  float S = rb[0] + rb[1] + rb[2] + rb[3];
  float S2 = rb[4] + rb[5] + rb[6] + rb[7];
  float mu = S * (1.f / 1024.f);
  float var = S2 * (1.f / 1024.f) - mu * mu;
  float rstd = rsqrtf(var + 1e-5f);
  f32x4 go = *(const f32x4*)&gw[tid * 4];
  f32x4 bo = *(const f32x4*)&bw[tid * 4];
  f32x4 r;
#pragma unroll
  for (int j = 0; j < 4; j++) r[j] = (v[j] - mu) * rstd * go[j] + bo[j];
  *(f32x4*)&O[(size_t)row * 1024 + tid * 4] = r;
  if (Ob) {
    u16x4 o;
#pragma unroll
    for (int j = 0; j < 4; j++) o[j] = f2bf(r[j]);
    *(u16x4*)&Ob[(size_t)row * 1024 + tid * 4] = o;
  }
}

// ---------------------------------------------------------------------------
extern "C" void kernel_launch(void* const* d_in, const int* in_sizes, int n_in,
                              void* d_out, int out_size, void* d_ws, size_t ws_size,
                              hipStream_t stream)
{
  const float* tgt  = (const float*)d_in[0];
  const float* mem  = (const float*)d_in[1];
  const float* saWq = (const float*)d_in[3];
  const float* sabq = (const float*)d_in[4];
  const float* saWo = (const float*)d_in[5];
  const float* sabo = (const float*)d_in[6];
  const float* caWq = (const float*)d_in[7];
  const float* cabq = (const float*)d_in[8];
  const float* caWo = (const float*)d_in[9];
  const float* cabo = (const float*)d_in[10];
  const float* W1   = (const float*)d_in[11];
  const float* b1   = (const float*)d_in[12];
  const float* W2   = (const float*)d_in[13];
  const float* b2   = (const float*)d_in[14];
  const float* g1   = (const float*)d_in[15];
  const float* be1  = (const float*)d_in[16];
  const float* g2   = (const float*)d_in[17];
  const float* be2  = (const float*)d_in[18];
  const float* g3   = (const float*)d_in[19];
  const float* be3  = (const float*)d_in[20];
  float* out = (float*)d_out;

  char* ws = (char*)d_ws;
  const size_t ACT2 = (size_t)4096 * 1024 * 2;
  unsigned short* qkvb  = (unsigned short*)ws; ws += ACT2;
  unsigned short* kvb   = (unsigned short*)ws; ws += ACT2;
  unsigned short* attnb = (unsigned short*)ws; ws += ACT2;
  unsigned short* x1b   = (unsigned short*)ws; ws += ACT2;
  unsigned short* x2b   = (unsigned short*)ws; ws += ACT2;
  unsigned short* WqTsaH = (unsigned short*)ws; ws += (size_t)1024 * 1024 * 2;
  unsigned short* WqTsaL = (unsigned short*)ws; ws += (size_t)1024 * 1024 * 2;
  unsigned short* WoTsa  = (unsigned short*)ws; ws += (size_t)1024 * 1024 * 2;
  unsigned short* WqTcaH = (unsigned short*)ws; ws += (size_t)1024 * 1024 * 2;
  unsigned short* WqTcaL = (unsigned short*)ws; ws += (size_t)1024 * 1024 * 2;
  unsigned short* WoTca  = (unsigned short*)ws; ws += (size_t)1024 * 1024 * 2;
  unsigned short* W1T   = (unsigned short*)ws; ws += (size_t)4096 * 1024 * 2;
  unsigned short* W2T   = (unsigned short*)ws; ws += (size_t)4096 * 1024 * 2;
  float* x2f  = (float*)ws; ws += (size_t)4096 * 1024 * 4;
  unsigned short* hb = (unsigned short*)ws; ws += (size_t)4096 * 4096 * 2;
  float* rAS  = (float*)ws; ws += (size_t)4096 * 32 * 4;
  float* wrelsa = (float*)ws; ws += (size_t)1024 * 32 * 4;
  float* wrelca = (float*)ws; ws += (size_t)1024 * 32 * 4;
  float* crelsa = (float*)ws; ws += 128;
  float* crelca = (float*)ws; ws += 128;
  float* x1f = out;   // d_out doubles as x1 f32 scratch

  dim3 blk(256);

  // ---------------- pre-pass ----------------
  transpose_cvt2_k<<<dim3(256), blk, 0, stream>>>(saWq, WqTsaH, WqTsaL, 1024, 1024);
  transpose_cvt2_k<<<dim3(256), blk, 0, stream>>>(caWq, WqTcaH, WqTcaL, 1024, 1024);
  transpose_cvt_k<<<dim3(256),  blk, 0, stream>>>(saWo, WoTsa, 1024, 1024);
  transpose_cvt_k<<<dim3(256),  blk, 0, stream>>>(caWo, WoTca, 1024, 1024);
  transpose_cvt_k<<<dim3(1024), blk, 0, stream>>>(W1, W1T, 1024, 4096);
  transpose_cvt_k<<<dim3(1024), blk, 0, stream>>>(W2, W2T, 4096, 1024);
  wrelbuild_k<<<dim3(64), blk, 0, stream>>>(saWq, wrelsa);
  wrelbuild_k<<<dim3(64), blk, 0, stream>>>(caWq, wrelca);
  crel_k<<<dim3(1), dim3(64), 0, stream>>>(sabq, crelsa);
  crel_k<<<dim3(1), dim3(64), 0, stream>>>(cabq, crelca);

  // ---------------- main pipeline ----------------
  sgemm_k<<<dim3(256), blk, 0, stream>>>(tgt, WqTsaH, WqTsaL, sabq, qkvb, 4096, 1024, 1024, 3);
  relgemm_k<<<dim3(512), blk, 0, stream>>>(tgt, wrelsa, crelsa, rAS);
  attn_k<true><<<dim3(64, 16), blk, 0, stream>>>(qkvb, qkvb, rAS, attnb);
  bgemm_k<false, true, false><<<dim3(256), blk, 0, stream>>>(attnb, WoTsa, sabo, tgt, x1f, 4096, 1024, 1024, 3);
  ln_k<<<dim3(4096), blk, 0, stream>>>(x1f, g1, be1, x1f, x1b);
  sgemm_k<<<dim3(256), blk, 0, stream>>>(x1f, WqTcaH, WqTcaL, cabq, qkvb, 4096, 1024, 1024, 3);
  sgemm_k<<<dim3(256), blk, 0, stream>>>(mem, WqTcaH, WqTcaL, cabq, kvb, 4096, 1024, 1024, 3);
  relgemm_k<<<dim3(512), blk, 0, stream>>>(x1f, wrelca, crelca, rAS);
  attn_k<false><<<dim3(64, 16), blk, 0, stream>>>(qkvb, kvb, rAS, attnb);
  bgemm_k<false, true, false><<<dim3(256), blk, 0, stream>>>(attnb, WoTca, cabo, x1f, x2f, 4096, 1024, 1024, 3);
  ln_k<<<dim3(4096), blk, 0, stream>>>(x2f, g2, be2, x2f, x2b);
  bgemm_k<true, false, true><<<dim3(1024), blk, 0, stream>>>(x2b, W1T, b1, nullptr, hb, 4096, 4096, 1024, 5);
  bgemm_k<false, true, false><<<dim3(256), blk, 0, stream>>>(hb, W2T, b2, x2f, out, 4096, 1024, 4096, 3);
  ln_k<<<dim3(4096), blk, 0, stream>>>(out, g3, be3, out, nullptr);

  (void)in_sizes; (void)n_in; (void)out_size; (void)ws_size;
}